// Round 2
// baseline (1049.591 us; speedup 1.0000x reference)
//
#include <hip/hip_runtime.h>
#include <stdint.h>

#define LDIM 1024
#define DDIM 256
#define FDIM 32
#define NSEG 64
#define BM 64
#define BK 64
#define NWAVE 4

typedef __attribute__((ext_vector_type(4))) float f32x4;
typedef __attribute__((ext_vector_type(8))) short short8;
typedef __attribute__((ext_vector_type(4))) unsigned int u32x4;

__device__ __forceinline__ unsigned int pk2bf(float a, float b) {
  union { float f; unsigned int u; } x, y; x.f = a; y.f = b;
  unsigned int ua = x.u + 0x7FFFu + ((x.u >> 16) & 1u);
  unsigned int ub = y.u + 0x7FFFu + ((y.u >> 16) & 1u);
  return (ua >> 16) | (ub & 0xFFFF0000u);
}

__device__ __forceinline__ unsigned short f2bf(float f) {
  union { float f; unsigned int u; } v; v.f = f;
  unsigned int r = v.u + 0x7FFFu + ((v.u >> 16) & 1u);
  return (unsigned short)(r >> 16);
}

// ---- prep: W1^T (bf16) rows 0..255, (W1@Wa1)^T rows 256..287 into ws ----
__global__ void prep_w1t(const float* __restrict__ W1, const float* __restrict__ Wa1,
                         unsigned short* __restrict__ w1t) {
  __shared__ float rowf[DDIM];
  const int k = blockIdx.x;
  const int t = threadIdx.x;
  float v = W1[(size_t)k * DDIM + t];
  rowf[t] = v;
  w1t[(size_t)t * LDIM + k] = f2bf(v);
  __syncthreads();
  if (t < FDIM) {
    float a = 0.f;
    for (int c = 0; c < DDIM; ++c) a += rowf[c] * Wa1[c * FDIM + t];
    w1t[(size_t)(DDIM + t) * LDIM + k] = f2bf(a);
  }
}

// ---- prep: zero accumulators, bz = b1@Wa1 + ba1 ----
__global__ void prep_misc(const float* __restrict__ b1, const float* __restrict__ Wa1,
                          const float* __restrict__ ba1, float* __restrict__ bz,
                          float* __restrict__ acc_eh, float* __restrict__ accE) {
  const int b = blockIdx.x, t = threadIdx.x;
  acc_eh[b * DDIM + t] = 0.f;
  if (t == 0) accE[b] = 0.f;
  if (b == 0 && t < FDIM) {
    float a = ba1[t];
    for (int c = 0; c < DDIM; ++c) a += b1[c] * Wa1[c * FDIM + t];
    bz[t] = a;
  }
}

// ---- main fused kernel: GEMM(bf16 MFMA, N=288 incl. z) + logits + segment accum ----
__global__ __launch_bounds__(256, 3) void fused_main(
    const float* __restrict__ x, const int* __restrict__ idxs,
    const unsigned short* __restrict__ w1t, const float* __restrict__ bz,
    const float* __restrict__ Wa2, const float* __restrict__ ba2,
    float* __restrict__ acc_eh, float* __restrict__ accE)
{
  __shared__ __align__(16) unsigned short xlds[BM][72];      // 64 rows x 144B (2-way free)
  __shared__ __align__(16) unsigned char blds[288 * 128];    // 288 rows x 128B, XOR-swizzled
  __shared__ float logit_s[BM];
  __shared__ float e_s[BM];
  __shared__ int seg_s[BM];

  const int tid = threadIdx.x;
  const int lane = tid & 63;
  const int wid = tid >> 6;       // 0..3
  const int wr = wid >> 1;        // 0..1 : 32-row half
  const int wc = wid & 1;         // 0..1 : 144-col half
  const int g = lane >> 4;
  const int cl = lane & 15;
  const int row0 = blockIdx.x * BM;

  if (tid < BM) seg_s[tid] = idxs[row0 + tid];

  f32x4 acc[2][9];
  const f32x4 zero4 = {0.f, 0.f, 0.f, 0.f};
  #pragma unroll
  for (int m = 0; m < 2; ++m)
    #pragma unroll
    for (int n = 0; n < 9; ++n) acc[m][n] = zero4;

  const int arow = tid >> 2;
  const int aq = tid & 3;
  const char* w1tb = (const char*)w1t;

  f32x4 r0, r1, r2, r3;
  {
    const float* gx = x + (size_t)(row0 + arow) * LDIM + aq * 16;
    r0 = *(const f32x4*)(gx);
    r1 = *(const f32x4*)(gx + 4);
    r2 = *(const f32x4*)(gx + 8);
    r3 = *(const f32x4*)(gx + 12);
  }

  #pragma unroll 1
  for (int kt = 0; kt < 16; ++kt) {
    __syncthreads();   // prev MFMA reads done; A regs arrived (compiler vmcnt)
    // B stage first (latency covered by the pack below)
    #pragma unroll
    for (int j = 0; j < 9; ++j) {
      int byteoff = j * 4096 + tid * 16;
      int brow = byteoff >> 7;
      int bcolb = byteoff & 127;
      int srcb = brow * 2048 + kt * 128 + (bcolb ^ ((brow & 7) << 4));
      __builtin_amdgcn_global_load_lds(
          (const __attribute__((address_space(1))) unsigned int*)(w1tb + srcb),
          (__attribute__((address_space(3))) unsigned int*)(blds + j * 4096 + wid * 1024),
          16, 0, 0);
    }
    // A: regs -> bf16 -> LDS
    u32x4 p0, p1;
    p0[0] = pk2bf(r0[0], r0[1]); p0[1] = pk2bf(r0[2], r0[3]);
    p0[2] = pk2bf(r1[0], r1[1]); p0[3] = pk2bf(r1[2], r1[3]);
    p1[0] = pk2bf(r2[0], r2[1]); p1[1] = pk2bf(r2[2], r2[3]);
    p1[2] = pk2bf(r3[0], r3[1]); p1[3] = pk2bf(r3[2], r3[3]);
    *(u32x4*)&xlds[arow][aq * 16] = p0;
    *(u32x4*)&xlds[arow][aq * 16 + 8] = p1;
    __syncthreads();   // B arrived + A writes visible
    // prefetch next A tile (drained at next iter's first barrier, covered by MFMA)
    if (kt < 15) {
      const float* gx = x + (size_t)(row0 + arow) * LDIM + (kt + 1) * BK + aq * 16;
      r0 = *(const f32x4*)(gx);
      r1 = *(const f32x4*)(gx + 4);
      r2 = *(const f32x4*)(gx + 8);
      r3 = *(const f32x4*)(gx + 12);
    }
    #pragma unroll
    for (int kk = 0; kk < 2; ++kk) {
      short8 af0 = *(const short8*)((const char*)xlds + (wr * 32 + cl) * 144 + kk * 64 + g * 16);
      short8 af1 = *(const short8*)((const char*)xlds + (wr * 32 + 16 + cl) * 144 + kk * 64 + g * 16);
      #pragma unroll
      for (int n = 0; n < 9; ++n) {
        int brr = wc * 144 + n * 16 + cl;
        short8 bf = *(const short8*)(blds + brr * 128 + ((kk * 64 + g * 16) ^ ((brr & 7) << 4)));
        acc[0][n] = __builtin_amdgcn_mfma_f32_16x16x32_bf16(af0, bf, acc[0][n], 0, 0, 0);
        acc[1][n] = __builtin_amdgcn_mfma_f32_16x16x32_bf16(af1, bf, acc[1][n], 0, 0, 0);
      }
    }
  }

  // ---- logits: z lives in acc frags n=7 (f=cl) and n=8 (f=16+cl) of wc==1 waves ----
  if (wc == 1) {
    const float w2a = Wa2[cl], w2b = Wa2[16 + cl];
    const float bza = bz[cl], bzb = bz[16 + cl];
    #pragma unroll
    for (int m = 0; m < 2; ++m) {
      float p[4];
      #pragma unroll
      for (int q = 0; q < 4; ++q) {
        float ea = exp2f((acc[m][7][q] + bza) * 2.8853900817779268f);
        float eb = exp2f((acc[m][8][q] + bzb) * 2.8853900817779268f);
        p[q] = (1.f - 2.f / (ea + 1.f)) * w2a + (1.f - 2.f / (eb + 1.f)) * w2b;
      }
      #pragma unroll
      for (int mask = 1; mask <= 8; mask <<= 1)
        #pragma unroll
        for (int q = 0; q < 4; ++q) p[q] += __shfl_xor(p[q], mask);
      if (cl == 0) {
        #pragma unroll
        for (int q = 0; q < 4; ++q)
          logit_s[wr * 32 + m * 16 + g * 4 + q] = p[q];
      }
    }
  }
  __syncthreads();
  if (tid < BM) e_s[tid] = expf(logit_s[tid] + ba2[0]);
  __syncthreads();

  // ---- per-segment weighted accumulation of H columns + sum of e ----
  const int smin = seg_s[0];
  const int smax = seg_s[BM - 1];
  float ev[8]; int sv[8];
  #pragma unroll
  for (int m = 0; m < 2; ++m)
    #pragma unroll
    for (int q = 0; q < 4; ++q) {
      int rl = wr * 32 + m * 16 + g * 4 + q;
      ev[m * 4 + q] = e_s[rl];
      sv[m * 4 + q] = seg_s[rl];
    }
  const int nmax = (wc == 0) ? 9 : 7;   // wc==1 frags 7,8 are z, not H
  for (int s = smin; s <= smax; ++s) {
    float wv[8];
    #pragma unroll
    for (int i = 0; i < 8; ++i) wv[i] = (sv[i] == s) ? ev[i] : 0.f;
    for (int n = 0; n < nmax; ++n) {
      float cs = 0.f;
      #pragma unroll
      for (int m = 0; m < 2; ++m)
        #pragma unroll
        for (int q = 0; q < 4; ++q)
          cs += wv[m * 4 + q] * acc[m][n][q];
      cs += __shfl_xor(cs, 16);
      cs += __shfl_xor(cs, 32);
      if (lane < 16) atomicAdd(&acc_eh[s * DDIM + wc * 144 + n * 16 + cl], cs);
    }
    if (wid == 0) {
      float v = (seg_s[lane] == s) ? e_s[lane] : 0.f;
      #pragma unroll
      for (int mask = 1; mask <= 32; mask <<= 1) v += __shfl_xor(v, mask);
      if (lane == 0) atomicAdd(&accE[s], v);
    }
  }
}

// ---- finalize: M = acc/Sum_e + b1; proj = normalize(M@Wp + bp) ----
__global__ void finalize_k(const float* __restrict__ acc_eh, const float* __restrict__ accE,
                           const float* __restrict__ b1, const float* __restrict__ Wp,
                           const float* __restrict__ bp, float* __restrict__ out) {
  __shared__ float Ml[DDIM];
  const int s = blockIdx.x, t = threadIdx.x;
  const float E = accE[s];
  float m = 0.f;
  if (E > 0.f) m = acc_eh[s * DDIM + t] / E + b1[t];
  out[s * DDIM + t] = m;
  Ml[t] = m;
  __syncthreads();
  if (t < FDIM) {
    float p = bp[t];
    for (int c = 0; c < DDIM; ++c) p += Ml[c] * Wp[c * FDIM + t];
    float n2 = p * p;
    #pragma unroll
    for (int mask = 1; mask <= 16; mask <<= 1) n2 += __shfl_xor(n2, mask);
    out[NSEG * DDIM + s * FDIM + t] = p / fmaxf(sqrtf(n2), 1e-12f);
  }
}

extern "C" void kernel_launch(void* const* d_in, const int* in_sizes, int n_in,
                              void* d_out, int out_size, void* d_ws, size_t ws_size,
                              hipStream_t stream) {
  const float* x   = (const float*)d_in[0];
  const int*   idxs= (const int*)d_in[1];
  const float* W1  = (const float*)d_in[2];
  const float* b1  = (const float*)d_in[3];
  const float* Wa1 = (const float*)d_in[4];
  const float* ba1 = (const float*)d_in[5];
  const float* Wa2 = (const float*)d_in[6];
  const float* ba2 = (const float*)d_in[7];
  const float* Wp  = (const float*)d_in[8];
  const float* bp  = (const float*)d_in[9];
  float* out = (float*)d_out;

  char* ws = (char*)d_ws;
  unsigned short* w1t = (unsigned short*)ws;          // 288*1024 bf16 (alloc 320 rows)
  float* bz     = (float*)(ws + 655360);              // 32 f32
  float* acc_eh = (float*)(ws + 655488);              // 64*256 f32
  float* accE   = (float*)(ws + 721024);              // 64 f32

  const int n = in_sizes[1];                          // 262144 rows
  prep_w1t<<<LDIM, DDIM, 0, stream>>>(W1, Wa1, w1t);
  prep_misc<<<NSEG, DDIM, 0, stream>>>(b1, Wa1, ba1, bz, acc_eh, accE);
  fused_main<<<n / BM, 256, 0, stream>>>(x, idxs, w1t, bz, Wa2, ba2, acc_eh, accE);
  finalize_k<<<NSEG, DDIM, 0, stream>>>(acc_eh, accE, b1, Wp, bp, out);
}

// Round 3
// 291.169 us; speedup vs baseline: 3.6047x; 3.6047x over previous
//
#include <hip/hip_runtime.h>
#include <stdint.h>

#define LDIM 1024
#define DDIM 256
#define FDIM 32
#define NSEG 64
#define BM 64
#define BK 64

typedef __attribute__((ext_vector_type(4))) float f32x4;
typedef __attribute__((ext_vector_type(8))) short short8;
typedef __attribute__((ext_vector_type(4))) unsigned int u32x4;

__device__ __forceinline__ unsigned int pk2bf(float a, float b) {
  union { float f; unsigned int u; } x, y; x.f = a; y.f = b;
  unsigned int ua = x.u + 0x7FFFu + ((x.u >> 16) & 1u);
  unsigned int ub = y.u + 0x7FFFu + ((y.u >> 16) & 1u);
  return (ua >> 16) | (ub & 0xFFFF0000u);
}

__device__ __forceinline__ unsigned short f2bf(float f) {
  union { float f; unsigned int u; } v; v.f = f;
  unsigned int r = v.u + 0x7FFFu + ((v.u >> 16) & 1u);
  return (unsigned short)(r >> 16);
}

// ---- prep: W1^T (bf16) rows 0..255, (W1@Wa1)^T rows 256..287 into ws ----
__global__ void prep_w1t(const float* __restrict__ W1, const float* __restrict__ Wa1,
                         unsigned short* __restrict__ w1t) {
  __shared__ float rowf[DDIM];
  const int k = blockIdx.x;
  const int t = threadIdx.x;
  float v = W1[(size_t)k * DDIM + t];
  rowf[t] = v;
  w1t[(size_t)t * LDIM + k] = f2bf(v);
  __syncthreads();
  if (t < FDIM) {
    float a = 0.f;
    for (int c = 0; c < DDIM; ++c) a += rowf[c] * Wa1[c * FDIM + t];
    w1t[(size_t)(DDIM + t) * LDIM + k] = f2bf(a);
  }
}

// ---- prep: zero accumulators, bz = b1@Wa1 + ba1 ----
__global__ void prep_misc(const float* __restrict__ b1, const float* __restrict__ Wa1,
                          const float* __restrict__ ba1, float* __restrict__ bz,
                          float* __restrict__ acc_eh, float* __restrict__ accE) {
  const int b = blockIdx.x, t = threadIdx.x;
  acc_eh[b * DDIM + t] = 0.f;
  if (t == 0) accE[b] = 0.f;
  if (b == 0 && t < FDIM) {
    float a = ba1[t];
    for (int c = 0; c < DDIM; ++c) a += b1[c] * Wa1[c * FDIM + t];
    bz[t] = a;
  }
}

// ---- main fused kernel: GEMM(bf16 MFMA, N=288 incl. z) + logits + segment accum ----
__global__ __launch_bounds__(256, 3) void fused_main(
    const float* __restrict__ x, const int* __restrict__ idxs,
    const unsigned short* __restrict__ w1t, const float* __restrict__ bz,
    const float* __restrict__ Wa2, const float* __restrict__ ba2,
    float* __restrict__ acc_eh, float* __restrict__ accE)
{
  __shared__ __align__(16) unsigned short xlds[BM][72];      // 64 rows x 144B (2-way free)
  __shared__ __align__(16) unsigned char blds[288 * 128];    // 288 rows x 128B, XOR-swizzled
  __shared__ float logit_s[BM];
  __shared__ float e_s[BM];
  __shared__ int seg_s[BM];

  const int tid = threadIdx.x;
  const int lane = tid & 63;
  const int wid = tid >> 6;       // 0..3
  const int wr = wid >> 1;        // 0..1 : 32-row half
  const int wc = wid & 1;         // 0..1 : 144-col half
  const int g = lane >> 4;
  const int cl = lane & 15;
  const int row0 = blockIdx.x * BM;

  if (tid < BM) seg_s[tid] = idxs[row0 + tid];

  f32x4 acc[2][9];
  const f32x4 zero4 = {0.f, 0.f, 0.f, 0.f};
  #pragma unroll
  for (int m = 0; m < 2; ++m)
    #pragma unroll
    for (int n = 0; n < 9; ++n) acc[m][n] = zero4;

  const int arow = tid >> 2;
  const int aq = tid & 3;
  const char* w1tb = (const char*)w1t;

  f32x4 r0, r1, r2, r3;
  {
    const float* gx = x + (size_t)(row0 + arow) * LDIM + aq * 16;
    r0 = *(const f32x4*)(gx);
    r1 = *(const f32x4*)(gx + 4);
    r2 = *(const f32x4*)(gx + 8);
    r3 = *(const f32x4*)(gx + 12);
  }

  #pragma unroll 1
  for (int kt = 0; kt < 16; ++kt) {
    __syncthreads();   // prev MFMA reads done; A regs arrived (compiler vmcnt)
    // B stage first (latency covered by the pack below)
    #pragma unroll
    for (int j = 0; j < 9; ++j) {
      int byteoff = j * 4096 + tid * 16;
      int brow = byteoff >> 7;
      int bcolb = byteoff & 127;
      int srcb = brow * 2048 + kt * 128 + (bcolb ^ ((brow & 7) << 4));
      __builtin_amdgcn_global_load_lds(
          (const __attribute__((address_space(1))) unsigned int*)(w1tb + srcb),
          (__attribute__((address_space(3))) unsigned int*)(blds + j * 4096 + wid * 1024),
          16, 0, 0);
    }
    // A: regs -> bf16 -> LDS
    u32x4 p0, p1;
    p0[0] = pk2bf(r0[0], r0[1]); p0[1] = pk2bf(r0[2], r0[3]);
    p0[2] = pk2bf(r1[0], r1[1]); p0[3] = pk2bf(r1[2], r1[3]);
    p1[0] = pk2bf(r2[0], r2[1]); p1[1] = pk2bf(r2[2], r2[3]);
    p1[2] = pk2bf(r3[0], r3[1]); p1[3] = pk2bf(r3[2], r3[3]);
    *(u32x4*)&xlds[arow][aq * 16] = p0;
    *(u32x4*)&xlds[arow][aq * 16 + 8] = p1;
    __syncthreads();   // B arrived + A writes visible
    // prefetch next A tile (drained at next iter's first barrier, covered by MFMA)
    if (kt < 15) {
      const float* gx = x + (size_t)(row0 + arow) * LDIM + (kt + 1) * BK + aq * 16;
      r0 = *(const f32x4*)(gx);
      r1 = *(const f32x4*)(gx + 4);
      r2 = *(const f32x4*)(gx + 8);
      r3 = *(const f32x4*)(gx + 12);
    }
    #pragma unroll
    for (int kk = 0; kk < 2; ++kk) {
      short8 af0 = *(const short8*)((const char*)xlds + (wr * 32 + cl) * 144 + kk * 64 + g * 16);
      short8 af1 = *(const short8*)((const char*)xlds + (wr * 32 + 16 + cl) * 144 + kk * 64 + g * 16);
      #pragma unroll
      for (int n = 0; n < 9; ++n) {
        int brr = wc * 144 + n * 16 + cl;
        short8 bf = *(const short8*)(blds + brr * 128 + ((kk * 64 + g * 16) ^ ((brr & 7) << 4)));
        acc[0][n] = __builtin_amdgcn_mfma_f32_16x16x32_bf16(af0, bf, acc[0][n], 0, 0, 0);
        acc[1][n] = __builtin_amdgcn_mfma_f32_16x16x32_bf16(af1, bf, acc[1][n], 0, 0, 0);
      }
    }
  }

  // ---- logits: z lives in acc frags n=7 (f=cl) and n=8 (f=16+cl) of wc==1 waves ----
  if (wc == 1) {
    const float w2a = Wa2[cl], w2b = Wa2[16 + cl];
    const float bza = bz[cl], bzb = bz[16 + cl];
    #pragma unroll
    for (int m = 0; m < 2; ++m) {
      float p[4];
      #pragma unroll
      for (int q = 0; q < 4; ++q) {
        float ea = exp2f((acc[m][7][q] + bza) * 2.8853900817779268f);
        float eb = exp2f((acc[m][8][q] + bzb) * 2.8853900817779268f);
        p[q] = (1.f - 2.f / (ea + 1.f)) * w2a + (1.f - 2.f / (eb + 1.f)) * w2b;
      }
      #pragma unroll
      for (int mask = 1; mask <= 8; mask <<= 1)
        #pragma unroll
        for (int q = 0; q < 4; ++q) p[q] += __shfl_xor(p[q], mask);
      if (cl == 0) {
        #pragma unroll
        for (int q = 0; q < 4; ++q)
          logit_s[wr * 32 + m * 16 + g * 4 + q] = p[q];
      }
    }
  }
  __syncthreads();
  if (tid < BM) e_s[tid] = expf(logit_s[tid] + ba2[0]);
  __syncthreads();

  // ---- per-segment weighted accumulation of H columns + sum of e ----
  // NOTE: n-loop MUST be compile-time unrolled — runtime-indexed acc[][] demotes
  // the whole accumulator to scratch (rule #20; round-2 regression: 5 GB scratch writes).
  const int smin = seg_s[0];
  const int smax = seg_s[BM - 1];
  float ev[8]; int sv[8];
  #pragma unroll
  for (int m = 0; m < 2; ++m)
    #pragma unroll
    for (int q = 0; q < 4; ++q) {
      int rl = wr * 32 + m * 16 + g * 4 + q;
      ev[m * 4 + q] = e_s[rl];
      sv[m * 4 + q] = seg_s[rl];
    }
  for (int s = smin; s <= smax; ++s) {
    float wv[8];
    #pragma unroll
    for (int i = 0; i < 8; ++i) wv[i] = (sv[i] == s) ? ev[i] : 0.f;
    #pragma unroll
    for (int n = 0; n < 9; ++n) {
      if (n < 7 || wc == 0) {          // wave-uniform predicate; indices stay static
        float cs = 0.f;
        #pragma unroll
        for (int m = 0; m < 2; ++m)
          #pragma unroll
          for (int q = 0; q < 4; ++q)
            cs += wv[m * 4 + q] * acc[m][n][q];
        cs += __shfl_xor(cs, 16);
        cs += __shfl_xor(cs, 32);
        if (lane < 16) atomicAdd(&acc_eh[s * DDIM + wc * 144 + n * 16 + cl], cs);
      }
    }
    if (wid == 0) {
      float v = (seg_s[lane] == s) ? e_s[lane] : 0.f;
      #pragma unroll
      for (int mask = 1; mask <= 32; mask <<= 1) v += __shfl_xor(v, mask);
      if (lane == 0) atomicAdd(&accE[s], v);
    }
  }
}

// ---- finalize: M = acc/Sum_e + b1; proj = normalize(M@Wp + bp) ----
__global__ void finalize_k(const float* __restrict__ acc_eh, const float* __restrict__ accE,
                           const float* __restrict__ b1, const float* __restrict__ Wp,
                           const float* __restrict__ bp, float* __restrict__ out) {
  __shared__ float Ml[DDIM];
  const int s = blockIdx.x, t = threadIdx.x;
  const float E = accE[s];
  float m = 0.f;
  if (E > 0.f) m = acc_eh[s * DDIM + t] / E + b1[t];
  out[s * DDIM + t] = m;
  Ml[t] = m;
  __syncthreads();
  if (t < FDIM) {
    float p = bp[t];
    for (int c = 0; c < DDIM; ++c) p += Ml[c] * Wp[c * FDIM + t];
    float n2 = p * p;
    #pragma unroll
    for (int mask = 1; mask <= 16; mask <<= 1) n2 += __shfl_xor(n2, mask);
    out[NSEG * DDIM + s * FDIM + t] = p / fmaxf(sqrtf(n2), 1e-12f);
  }
}

extern "C" void kernel_launch(void* const* d_in, const int* in_sizes, int n_in,
                              void* d_out, int out_size, void* d_ws, size_t ws_size,
                              hipStream_t stream) {
  const float* x   = (const float*)d_in[0];
  const int*   idxs= (const int*)d_in[1];
  const float* W1  = (const float*)d_in[2];
  const float* b1  = (const float*)d_in[3];
  const float* Wa1 = (const float*)d_in[4];
  const float* ba1 = (const float*)d_in[5];
  const float* Wa2 = (const float*)d_in[6];
  const float* ba2 = (const float*)d_in[7];
  const float* Wp  = (const float*)d_in[8];
  const float* bp  = (const float*)d_in[9];
  float* out = (float*)d_out;

  char* ws = (char*)d_ws;
  unsigned short* w1t = (unsigned short*)ws;          // 288*1024 bf16 (alloc 320 rows)
  float* bz     = (float*)(ws + 655360);              // 32 f32
  float* acc_eh = (float*)(ws + 655488);              // 64*256 f32
  float* accE   = (float*)(ws + 721024);              // 64 f32

  const int n = in_sizes[1];                          // 262144 rows
  prep_w1t<<<LDIM, DDIM, 0, stream>>>(W1, Wa1, w1t);
  prep_misc<<<NSEG, DDIM, 0, stream>>>(b1, Wa1, ba1, bz, acc_eh, accE);
  fused_main<<<n / BM, 256, 0, stream>>>(x, idxs, w1t, bz, Wa2, ba2, acc_eh, accE);
  finalize_k<<<NSEG, DDIM, 0, stream>>>(acc_eh, accE, b1, Wp, bp, out);
}